// Round 7
// baseline (166.533 us; speedup 1.0000x reference)
//
#include <hip/hip_runtime.h>
#include <hip/hip_bf16.h>
#include <math.h>

// Shapes (fixed by the reference problem)
#define BB 2
#define TT 2048
#define CC 512
#define HH 8
#define DD 64
#define KK 4
#define C3 1536
#define MROWS (BB*TT)          // 4096

typedef __attribute__((ext_vector_type(8))) short bf16x8;
typedef __attribute__((ext_vector_type(4))) float floatx4;

static __device__ __forceinline__ unsigned short f2bf(float f) {
  unsigned int u = __float_as_uint(f);
  return (unsigned short)((u + 0x7fffu + ((u >> 16) & 1u)) >> 16);
}
static __device__ __forceinline__ float bf2f(unsigned short u) {
  return __uint_as_float(((unsigned int)u) << 16);
}

// ---------------------------------------------------------------------------
// GEMM body: C[M,N] = A[M,K] @ Bt[N,K]^T + bias. 128x64 tile, BK=32,
// 256 thr (4 waves, each 64m x 32n). LDS chunk XOR-swizzle: the 16-B chunk
// stored at slot (row, c) is global chunk c ^ ((row>>1)&3) -> fragment
// ds_read_b128 is 2-way (free) instead of 8-way bank conflicted.
// ---------------------------------------------------------------------------
template<bool BF16OUT>
static __device__ __forceinline__ void gemm_body(
    int bid, int nt,
    const unsigned short* __restrict__ A,
    const unsigned short* __restrict__ Bt,
    const float* __restrict__ bias,
    void* __restrict__ Cout, int N, int K) {
  __shared__ bf16x8 As[128 * 4];   // [row][4 chunks of 8 bf16]
  __shared__ bf16x8 Bs[64 * 4];
  const int tid  = threadIdx.x;
  const int wave = tid >> 6;
  const int lane = tid & 63;
  const int n0 = (bid % nt) * 64;
  const int m0 = (bid / nt) * 128;
  const int m_off = (wave >> 1) * 64;
  const int n_off = (wave & 1) * 32;
  const int lrow = lane >> 2;                         // staging row 0..15
  const int lx   = ((lane & 3) ^ ((lane >> 3) & 3)) * 8;  // swizzled chunk (elems)
  const int fr = lane & 15;
  const int fq = lane >> 4;
  const int key = (fr >> 1) & 3;                      // read-side swizzle key

  floatx4 acc[4][2];
#pragma unroll
  for (int i = 0; i < 4; ++i)
#pragma unroll
    for (int j = 0; j < 2; ++j) acc[i][j] = (floatx4){0.f, 0.f, 0.f, 0.f};

  for (int k0 = 0; k0 < K; k0 += 32) {
#pragma unroll
    for (int s = 0; s < 2; ++s) {
      int q = wave * 2 + s;          // 0..7 -> 128 A rows
      const unsigned short* ga = A + (size_t)(m0 + q * 16 + lrow) * K + k0 + lx;
      __builtin_amdgcn_global_load_lds(
          (const __attribute__((address_space(1))) void*)ga,
          (__attribute__((address_space(3))) void*)((char*)As + q * 1024), 16, 0, 0);
    }
    const unsigned short* gb = Bt + (size_t)(n0 + wave * 16 + lrow) * K + k0 + lx;
    __builtin_amdgcn_global_load_lds(
        (const __attribute__((address_space(1))) void*)gb,
        (__attribute__((address_space(3))) void*)((char*)Bs + wave * 1024), 16, 0, 0);
    __syncthreads();
    bf16x8 a[4], b[2];
#pragma unroll
    for (int i = 0; i < 4; ++i)
      a[i] = As[(m_off + i * 16 + fr) * 4 + (fq ^ key)];
#pragma unroll
    for (int j = 0; j < 2; ++j)
      b[j] = Bs[(n_off + j * 16 + fr) * 4 + (fq ^ key)];
#pragma unroll
    for (int i = 0; i < 4; ++i)
#pragma unroll
      for (int j = 0; j < 2; ++j)
        acc[i][j] = __builtin_amdgcn_mfma_f32_16x16x32_bf16(a[i], b[j], acc[i][j], 0, 0, 0);
    __syncthreads();
  }
#pragma unroll
  for (int j = 0; j < 2; ++j) {
    int col = n0 + n_off + j * 16 + fr;
    float bv = bias[col];
#pragma unroll
    for (int i = 0; i < 4; ++i) {
#pragma unroll
      for (int r = 0; r < 4; ++r) {
        int row = m0 + m_off + i * 16 + fq * 4 + r;
        float v = acc[i][j][r] + bv;
        if (BF16OUT) ((unsigned short*)Cout)[(size_t)row * N + col] = f2bf(v);
        else         ((float*)Cout)[(size_t)row * N + col] = v;
      }
    }
  }
}

// ---------------------------------------------------------------------------
// transpose+convert body: W[R][Cn] fp32 -> Wt[.][R] bf16, 32x32 tiles
// ---------------------------------------------------------------------------
static __device__ __forceinline__ void transpose_body(
    int t, int nbx, const float* __restrict__ W, unsigned short* __restrict__ Wt,
    int R, int Cn) {
  __shared__ unsigned short tile[32][33];
  const int c0 = (t % nbx) * 32, r0 = (t / nbx) * 32;
  const int tx = threadIdx.x & 31, ty = threadIdx.x >> 5;
#pragma unroll
  for (int i = 0; i < 4; ++i) {
    int r = ty + i * 8;
    tile[r][tx] = f2bf(W[(size_t)(r0 + r) * Cn + c0 + tx]);
  }
  __syncthreads();
#pragma unroll
  for (int i = 0; i < 4; ++i) {
    int r = ty + i * 8;
    Wt[(size_t)(c0 + r) * R + r0 + tx] = tile[tx][r];
  }
}

// ---------------------------------------------------------------------------
// Kernel 1: all input conversions (x->bf16, Wqkv^T, Wproj^T)
// blocks: [0,1024) x-convert | [1024,1792) WqkvT | [1792,2048) WprojT
// ---------------------------------------------------------------------------
__global__ __launch_bounds__(256) void prep_kernel(
    const float* __restrict__ x, unsigned short* __restrict__ x_bf,
    const float* __restrict__ Wqkv, unsigned short* __restrict__ wqkv_t,
    const float* __restrict__ Wproj, unsigned short* __restrict__ wproj_t) {
  const int bid = blockIdx.x;
  if (bid < 1024) {                       // convert x: 2M elements, 8/thread
    int g = bid * 256 + threadIdx.x;
    const float4* p = (const float4*)x;
    float4 f0 = p[g * 2], f1 = p[g * 2 + 1];
    union { unsigned short u[8]; uint4 v; } pk;
    pk.u[0]=f2bf(f0.x); pk.u[1]=f2bf(f0.y); pk.u[2]=f2bf(f0.z); pk.u[3]=f2bf(f0.w);
    pk.u[4]=f2bf(f1.x); pk.u[5]=f2bf(f1.y); pk.u[6]=f2bf(f1.z); pk.u[7]=f2bf(f1.w);
    ((uint4*)x_bf)[g] = pk.v;
  } else if (bid < 1024 + 768) {          // Wqkv [512,1536] -> [1536,512]
    transpose_body(bid - 1024, C3 / 32, Wqkv, wqkv_t, CC, C3);
  } else {                                // Wproj [512,512] -> ^T
    transpose_body(bid - 1792, CC / 32, Wproj, wproj_t, CC, CC);
  }
}

// ---------------------------------------------------------------------------
// Kernel 2: qkv = x @ Wqkv + bqkv (bf16 out), 128x64 tiles, 768 blocks
// ---------------------------------------------------------------------------
__global__ __launch_bounds__(256) void gemm1_kernel(
    const unsigned short* __restrict__ x_bf,
    const unsigned short* __restrict__ wqkv_t,
    const float* __restrict__ bqkv,
    unsigned short* __restrict__ qkv_bf) {
  gemm_body<true>(blockIdx.x, C3 / 64, x_bf, wqkv_t, bqkv, qkv_bf, C3, CC);
}

// ---------------------------------------------------------------------------
// Kernel 3: fused per-row topk(tau) -> sparse attn (v-space) -> tau EMA.
// 512 threads: wave h = head h; tau row lives in registers throughout.
// ---------------------------------------------------------------------------
__global__ __launch_bounds__(512) void fused_attn_kernel(
    const unsigned short* __restrict__ qkv,   // [4096][1536] = q|k|v
    const float* __restrict__ tau,
    unsigned short* __restrict__ attn_bf,     // [4096][512] v-space attn out
    float* __restrict__ tau_new) {
  const int row  = blockIdx.x;
  const int b    = row >> 11;
  const int tid  = threadIdx.x;
  const int wave = tid >> 6;
  const int lane = tid & 63;
  const int h    = wave;

  // ---- tau row -> registers (4 per thread) ----
  float4 f = ((const float4*)(tau + (size_t)row * TT))[tid];
  float v[4] = { f.x, f.y, f.z, f.w };
  const int base = tid * 4;

  // ---- exact top-4, tie-break lower index (matches jax.lax.top_k) ----
  __shared__ float wv8[8];
  __shared__ int   wi8[8];
  __shared__ int   idx4[KK];
  __shared__ float tau4[KK];
  for (int r = 0; r < KK; ++r) {
    float bv = v[0]; int bi = base;
#pragma unroll
    for (int i = 1; i < 4; ++i)
      if (v[i] > bv) { bv = v[i]; bi = base + i; }   // strict > keeps lowest idx
#pragma unroll
    for (int off = 32; off > 0; off >>= 1) {
      float vv = __shfl_xor(bv, off, 64);
      int   ii = __shfl_xor(bi, off, 64);
      if (vv > bv || (vv == bv && ii < bi)) { bv = vv; bi = ii; }
    }
    if (lane == 0) { wv8[wave] = bv; wi8[wave] = bi; }
    __syncthreads();
    if (tid == 0) {
      float b2 = wv8[0]; int i2 = wi8[0];
#pragma unroll
      for (int k = 1; k < 8; ++k)
        if (wv8[k] > b2 || (wv8[k] == b2 && wi8[k] < i2)) { b2 = wv8[k]; i2 = wi8[k]; }
      idx4[r] = i2; tau4[r] = b2;
    }
    __syncthreads();
    int win = idx4[r];
    if ((win >> 2) == tid) v[win & 3] = -1e30f;   // mark; restored in EMA below
  }

  // ---- gather k, v at the 4 keys; logits; softmax (per wave/head) ----
  const float q = bf2f(qkv[(size_t)row * C3 + h * DD + lane]);
  float kj[KK], vj[KK];
#pragma unroll
  for (int j = 0; j < KK; ++j) {
    size_t bs = ((size_t)(b * TT + idx4[j])) * C3 + h * DD + lane;
    kj[j] = bf2f(qkv[bs + CC]);
    vj[j] = bf2f(qkv[bs + 2 * CC]);
  }
  float p[KK];
#pragma unroll
  for (int j = 0; j < KK; ++j) p[j] = q * kj[j];
#pragma unroll
  for (int off = 32; off > 0; off >>= 1)
#pragma unroll
    for (int j = 0; j < KK; ++j) p[j] += __shfl_xor(p[j], off, 64);

  float logit[KK];
#pragma unroll
  for (int j = 0; j < KK; ++j)
    logit[j] = p[j] * 0.125f + 2.5f * logf(tau4[j] + 1e-8f);
  float m = fmaxf(fmaxf(logit[0], logit[1]), fmaxf(logit[2], logit[3]));
  float den = 0.f;
#pragma unroll
  for (int j = 0; j < KK; ++j) { p[j] = expf(logit[j] - m); den += p[j]; }
  float inv = 1.f / den;
#pragma unroll
  for (int j = 0; j < KK; ++j) p[j] *= inv;

  // ---- attn output in v-space (bf16; projected by gemm2 afterwards) ----
  float o = 0.f;
#pragma unroll
  for (int j = 0; j < KK; ++j) o += p[j] * vj[j];
  attn_bf[(size_t)row * CC + h * DD + lane] = f2bf(o);

  // ---- signal = mean over heads of p; s3 = signal^3 ----
  __shared__ float ps[HH][KK];
  __shared__ float s3sh[KK];
  if (lane < KK) ps[h][lane] = p[lane];
  __syncthreads();
  if (tid < KK) {
    float s = 0.f;
#pragma unroll
    for (int k = 0; k < HH; ++k) s += ps[k][tid];
    s *= (1.0f / HH);
    s3sh[tid] = s * s * s;
  }
  __syncthreads();

  // ---- tau EMA + normalize + clip (row still in registers) ----
  const float keep = 1.0f - 0.085f;
  float t4[4];
  float local = 0.f;
#pragma unroll
  for (int i = 0; i < 4; ++i) {
    float t = keep * v[i];                       // winners hold -1e30 marks
#pragma unroll
    for (int j = 0; j < KK; ++j)
      if (base + i == idx4[j]) t = keep * tau4[j] + s3sh[j];  // restore+deposit
    t4[i] = t;
    local += t;
  }
#pragma unroll
  for (int off = 32; off > 0; off >>= 1) local += __shfl_xor(local, off, 64);
  __shared__ float wsum[8];
  __shared__ float tot;
  if (lane == 0) wsum[wave] = local;
  __syncthreads();
  if (tid == 0) {
    float s = 0.f;
#pragma unroll
    for (int k = 0; k < 8; ++k) s += wsum[k];
    tot = s;
  }
  __syncthreads();
  float ninv = 1.f / (tot + 1e-8f);
  float4 o4 = { fminf(t4[0] * ninv, 5.f), fminf(t4[1] * ninv, 5.f),
                fminf(t4[2] * ninv, 5.f), fminf(t4[3] * ninv, 5.f) };
  ((float4*)(tau_new + (size_t)row * TT))[tid] = o4;
}

// ---------------------------------------------------------------------------
// Kernel 4: out = attn_bf @ Wproj + bproj (fp32 out), 128x64 tiles, 256 blocks
// ---------------------------------------------------------------------------
__global__ __launch_bounds__(256) void gemm2_kernel(
    const unsigned short* __restrict__ attn_bf,
    const unsigned short* __restrict__ wproj_t,
    const float* __restrict__ bproj,
    float* __restrict__ out) {
  gemm_body<false>(blockIdx.x, CC / 64, attn_bf, wproj_t, bproj, out, CC, CC);
}

// ---------------------------------------------------------------------------
extern "C" void kernel_launch(void* const* d_in, const int* in_sizes, int n_in,
                              void* d_out, int out_size, void* d_ws, size_t ws_size,
                              hipStream_t stream) {
  const float* x     = (const float*)d_in[0];   // [B,T,C]
  const float* tau   = (const float*)d_in[1];   // [B,T,T]
  const float* Wqkv  = (const float*)d_in[2];   // [C,3C]
  const float* bqkv  = (const float*)d_in[3];   // [3C]
  const float* Wproj = (const float*)d_in[4];   // [C,C]
  const float* bproj = (const float*)d_in[5];   // [C]

  float* out     = (float*)d_out;               // [B,T,C]
  float* tau_new = out + (size_t)MROWS * CC;    // [B,T,T]

  char* w = (char*)d_ws;
  unsigned short* qkv_bf  = (unsigned short*)w; w += (size_t)MROWS * C3 * 2;
  unsigned short* x_bf    = (unsigned short*)w; w += (size_t)MROWS * CC * 2;
  unsigned short* wqkv_t  = (unsigned short*)w; w += (size_t)C3 * CC * 2;
  unsigned short* wproj_t = (unsigned short*)w; w += (size_t)CC * CC * 2;
  unsigned short* attn_bf = (unsigned short*)w;

  // 1) converts: x->bf16, Wqkv^T, Wproj^T
  prep_kernel<<<2048, 256, 0, stream>>>(x, x_bf, Wqkv, wqkv_t, Wproj, wproj_t);

  // 2) qkv = x @ Wqkv + bqkv (bf16), 128x64 tiles
  gemm1_kernel<<<(MROWS / 128) * (C3 / 64), 256, 0, stream>>>(
      x_bf, wqkv_t, bqkv, qkv_bf);

  // 3) fused: top-4 -> sparse attention (v-space) -> tau EMA/normalize/clip
  fused_attn_kernel<<<MROWS, 512, 0, stream>>>(qkv_bf, tau, attn_bf, tau_new);

  // 4) out = attn @ Wproj + bproj (fp32), 128x64 tiles
  gemm2_kernel<<<(MROWS / 128) * (CC / 64), 256, 0, stream>>>(
      attn_bf, wproj_t, bproj, out);
}

// Round 8
// 146.260 us; speedup vs baseline: 1.1386x; 1.1386x over previous
//
#include <hip/hip_runtime.h>
#include <hip/hip_bf16.h>
#include <math.h>

// Shapes (fixed by the reference problem)
#define BB 2
#define TT 2048
#define CC 512
#define HH 8
#define DD 64
#define KK 4
#define C3 1536
#define MROWS (BB*TT)          // 4096

// GEMM tiling: 128(m) x 64(n), BK=32, 256 threads (4 waves of 64x32)
#define G1_NT (C3/64)          // 24
#define G1_BLOCKS (G1_NT*(MROWS/128))  // 768
#define G2_NT (CC/64)          // 8
#define G2_BLOCKS (G2_NT*(MROWS/128))  // 256

typedef __attribute__((ext_vector_type(8))) short bf16x8;
typedef __attribute__((ext_vector_type(4))) float floatx4;

static __device__ __forceinline__ unsigned short f2bf(float f) {
  unsigned int u = __float_as_uint(f);
  return (unsigned short)((u + 0x7fffu + ((u >> 16) & 1u)) >> 16);
}
static __device__ __forceinline__ float bf2f(unsigned short u) {
  return __uint_as_float(((unsigned int)u) << 16);
}

// ---------------------------------------------------------------------------
// GEMM body (round-7 proven, XOR LDS swizzle): C = A[M,K] @ Bt[N,K]^T + bias
// 128x64 tile, BK=32, 256 thr (4 waves, each 64m x 32n).
// ---------------------------------------------------------------------------
template<bool BF16OUT>
static __device__ __forceinline__ void gemm_body(
    int bid, int nt,
    const unsigned short* __restrict__ A,
    const unsigned short* __restrict__ Bt,
    const float* __restrict__ bias,
    void* __restrict__ Cout, int N, int K) {
  __shared__ bf16x8 As[128 * 4];   // [row][4 chunks of 8 bf16]
  __shared__ bf16x8 Bs[64 * 4];
  const int tid  = threadIdx.x;
  const int wave = tid >> 6;
  const int lane = tid & 63;
  const int n0 = (bid % nt) * 64;
  const int m0 = (bid / nt) * 128;
  const int m_off = (wave >> 1) * 64;
  const int n_off = (wave & 1) * 32;
  const int lrow = lane >> 2;                             // staging row 0..15
  const int lx   = ((lane & 3) ^ ((lane >> 3) & 3)) * 8;  // swizzled chunk
  const int fr = lane & 15;
  const int fq = lane >> 4;
  const int key = (fr >> 1) & 3;                          // read-side key

  floatx4 acc[4][2];
#pragma unroll
  for (int i = 0; i < 4; ++i)
#pragma unroll
    for (int j = 0; j < 2; ++j) acc[i][j] = (floatx4){0.f, 0.f, 0.f, 0.f};

  for (int k0 = 0; k0 < K; k0 += 32) {
#pragma unroll
    for (int s = 0; s < 2; ++s) {
      int q = wave * 2 + s;          // 0..7 -> 128 A rows
      const unsigned short* ga = A + (size_t)(m0 + q * 16 + lrow) * K + k0 + lx;
      __builtin_amdgcn_global_load_lds(
          (const __attribute__((address_space(1))) void*)ga,
          (__attribute__((address_space(3))) void*)((char*)As + q * 1024), 16, 0, 0);
    }
    const unsigned short* gb = Bt + (size_t)(n0 + wave * 16 + lrow) * K + k0 + lx;
    __builtin_amdgcn_global_load_lds(
        (const __attribute__((address_space(1))) void*)gb,
        (__attribute__((address_space(3))) void*)((char*)Bs + wave * 1024), 16, 0, 0);
    __syncthreads();
    bf16x8 a[4], b[2];
#pragma unroll
    for (int i = 0; i < 4; ++i)
      a[i] = As[(m_off + i * 16 + fr) * 4 + (fq ^ key)];
#pragma unroll
    for (int j = 0; j < 2; ++j)
      b[j] = Bs[(n_off + j * 16 + fr) * 4 + (fq ^ key)];
#pragma unroll
    for (int i = 0; i < 4; ++i)
#pragma unroll
      for (int j = 0; j < 2; ++j)
        acc[i][j] = __builtin_amdgcn_mfma_f32_16x16x32_bf16(a[i], b[j], acc[i][j], 0, 0, 0);
    __syncthreads();
  }
#pragma unroll
  for (int j = 0; j < 2; ++j) {
    int col = n0 + n_off + j * 16 + fr;
    float bv = bias[col];
#pragma unroll
    for (int i = 0; i < 4; ++i) {
#pragma unroll
      for (int r = 0; r < 4; ++r) {
        int row = m0 + m_off + i * 16 + fq * 4 + r;
        float v = acc[i][j][r] + bv;
        if (BF16OUT) ((unsigned short*)Cout)[(size_t)row * N + col] = f2bf(v);
        else         ((float*)Cout)[(size_t)row * N + col] = v;
      }
    }
  }
}

// ---------------------------------------------------------------------------
// sorted top-4 helpers: total order (value desc, index asc) = jax.lax.top_k
// ---------------------------------------------------------------------------
static __device__ __forceinline__ bool kv_better(float av, int ai, float bv, int bi) {
  return av > bv || (av == bv && ai < bi);
}
static __device__ __forceinline__ void kv_ce(float* v, int* i, int a, int b) {
  if (!kv_better(v[a], i[a], v[b], i[b])) {
    float tv = v[a]; v[a] = v[b]; v[b] = tv;
    int   ti = i[a]; i[a] = i[b]; i[b] = ti;
  }
}
// a,b sorted desc; a <- top-4 of union, sorted desc (bitonic partial merge)
static __device__ __forceinline__ void kv_merge(
    float* av, int* ai, const float* bv, const int* bi) {
  float cv[4]; int ci[4];
#pragma unroll
  for (int j = 0; j < 4; ++j) {
    bool t = kv_better(av[j], ai[j], bv[3 - j], bi[3 - j]);
    cv[j] = t ? av[j] : bv[3 - j];
    ci[j] = t ? ai[j] : bi[3 - j];
  }
  kv_ce(cv, ci, 0, 2); kv_ce(cv, ci, 1, 3);
  kv_ce(cv, ci, 0, 1); kv_ce(cv, ci, 2, 3);
#pragma unroll
  for (int j = 0; j < 4; ++j) { av[j] = cv[j]; ai[j] = ci[j]; }
}

// ---------------------------------------------------------------------------
// top-4 body (fast): per-thread sorted-4 of 8 elems, 6-step butterfly bitonic
// merge, one barrier for the cross-wave merge. 256 threads.
// ---------------------------------------------------------------------------
static __device__ __forceinline__ void topk_body(
    int row, const float* __restrict__ tau, int* __restrict__ idx_out) {
  const int tid = threadIdx.x;
  const float4* rp = (const float4*)(tau + (size_t)row * TT);
  float4 f0 = rp[tid * 2], f1 = rp[tid * 2 + 1];
  float e[8] = { f0.x, f0.y, f0.z, f0.w, f1.x, f1.y, f1.z, f1.w };
  const int base = tid * 8;

  float tv[4] = { -1e30f, -1e30f, -1e30f, -1e30f };
  int   ti[4] = { 1 << 30, 1 << 30, 1 << 30, 1 << 30 };
#pragma unroll
  for (int k = 0; k < 8; ++k) {
    float v = e[k];
    if (v > tv[3]) {                 // strict >: increasing idx keeps earlier
      tv[3] = v; ti[3] = base + k;
      if (tv[3] > tv[2]) { float a=tv[2]; tv[2]=tv[3]; tv[3]=a; int b=ti[2]; ti[2]=ti[3]; ti[3]=b; }
      if (tv[2] > tv[1]) { float a=tv[1]; tv[1]=tv[2]; tv[2]=a; int b=ti[1]; ti[1]=ti[2]; ti[2]=b; }
      if (tv[1] > tv[0]) { float a=tv[0]; tv[0]=tv[1]; tv[1]=a; int b=ti[0]; ti[0]=ti[1]; ti[1]=b; }
    }
  }

  // butterfly allreduce across the wave (6 steps)
#pragma unroll
  for (int step = 1; step <= 32; step <<= 1) {
    float bv[4]; int bi[4];
#pragma unroll
    for (int j = 0; j < 4; ++j) {
      bv[j] = __shfl_xor(tv[j], step, 64);
      bi[j] = __shfl_xor(ti[j], step, 64);
    }
    kv_merge(tv, ti, bv, bi);
  }

  // cross-wave merge via LDS (4 waves)
  __shared__ float swv[4][4];
  __shared__ int   swi[4][4];
  const int wave = tid >> 6, lane = tid & 63;
  if (lane == 0) {
#pragma unroll
    for (int j = 0; j < 4; ++j) { swv[wave][j] = tv[j]; swi[wave][j] = ti[j]; }
  }
  __syncthreads();
  if (tid == 0) {
    float m0[4], m1[4]; int x0[4], x1[4];
#pragma unroll
    for (int j = 0; j < 4; ++j) { m0[j] = swv[0][j]; x0[j] = swi[0][j]; }
#pragma unroll
    for (int j = 0; j < 4; ++j) { m1[j] = swv[1][j]; x1[j] = swi[1][j]; }
    kv_merge(m0, x0, m1, x1);
#pragma unroll
    for (int j = 0; j < 4; ++j) { m1[j] = swv[2][j]; x1[j] = swi[2][j]; }
    float m2[4]; int x2[4];
#pragma unroll
    for (int j = 0; j < 4; ++j) { m2[j] = swv[3][j]; x2[j] = swi[3][j]; }
    kv_merge(m1, x1, m2, x2);
    kv_merge(m0, x0, m1, x1);
    int4 w = { x0[0], x0[1], x0[2], x0[3] };
    *((int4*)(idx_out + row * KK)) = w;
  }
}

// ---------------------------------------------------------------------------
// tau EMA + normalize + clip body (round-3 proven)
// ---------------------------------------------------------------------------
static __device__ __forceinline__ void tau_body(
    int row, const float* __restrict__ tau, const int* __restrict__ idx_in,
    const float* __restrict__ sig_in, float* __restrict__ tau_out) {
  const int tid = threadIdx.x;
  int i4[KK]; float s3[KK];
#pragma unroll
  for (int j = 0; j < KK; ++j) {
    i4[j] = idx_in[row * KK + j];
    float s = sig_in[row * KK + j];
    s3[j] = s * s * s;
  }
  const float4* rp = (const float4*)(tau + (size_t)row * TT);
  float v[8];
  float4 f0 = rp[tid * 2], f1 = rp[tid * 2 + 1];
  v[0]=f0.x; v[1]=f0.y; v[2]=f0.z; v[3]=f0.w;
  v[4]=f1.x; v[5]=f1.y; v[6]=f1.z; v[7]=f1.w;
  const float keep = 1.0f - 0.085f;
  const int base = tid * 8;
  float local = 0.f;
#pragma unroll
  for (int i = 0; i < 8; ++i) {
    float t = keep * v[i];
#pragma unroll
    for (int j = 0; j < KK; ++j)
      if (base + i == i4[j]) t += s3[j];
    v[i] = t;
    local += t;
  }
#pragma unroll
  for (int off = 32; off > 0; off >>= 1) local += __shfl_xor(local, off, 64);
  __shared__ float wsum[4];
  __shared__ float tot;
  if ((tid & 63) == 0) wsum[tid >> 6] = local;
  __syncthreads();
  if (tid == 0) tot = wsum[0] + wsum[1] + wsum[2] + wsum[3];
  __syncthreads();
  float inv = 1.f / (tot + 1e-8f);
  float4* op = (float4*)(tau_out + (size_t)row * TT);
  float4 o0 = { fminf(v[0]*inv,5.f), fminf(v[1]*inv,5.f), fminf(v[2]*inv,5.f), fminf(v[3]*inv,5.f) };
  float4 o1 = { fminf(v[4]*inv,5.f), fminf(v[5]*inv,5.f), fminf(v[6]*inv,5.f), fminf(v[7]*inv,5.f) };
  op[tid * 2] = o0;
  op[tid * 2 + 1] = o1;
}

// ---------------------------------------------------------------------------
// transpose+convert body: W[R][Cn] fp32 -> Wt[.][R] bf16, 32x32 tiles
// ---------------------------------------------------------------------------
static __device__ __forceinline__ void transpose_body(
    int t, int nbx, const float* __restrict__ W, unsigned short* __restrict__ Wt,
    int R, int Cn) {
  __shared__ unsigned short tile[32][33];
  const int c0 = (t % nbx) * 32, r0 = (t / nbx) * 32;
  const int tx = threadIdx.x & 31, ty = threadIdx.x >> 5;
#pragma unroll
  for (int i = 0; i < 4; ++i) {
    int r = ty + i * 8;
    tile[r][tx] = f2bf(W[(size_t)(r0 + r) * Cn + c0 + tx]);
  }
  __syncthreads();
#pragma unroll
  for (int i = 0; i < 4; ++i) {
    int r = ty + i * 8;
    Wt[(size_t)(c0 + r) * R + r0 + tx] = tile[tx][r];
  }
}

// ---------------------------------------------------------------------------
// Kernel 1: all input conversions (x->bf16, Wqkv^T, Wproj^T)
// ---------------------------------------------------------------------------
__global__ __launch_bounds__(256) void prep_kernel(
    const float* __restrict__ x, unsigned short* __restrict__ x_bf,
    const float* __restrict__ Wqkv, unsigned short* __restrict__ wqkv_t,
    const float* __restrict__ Wproj, unsigned short* __restrict__ wproj_t) {
  const int bid = blockIdx.x;
  if (bid < 1024) {                       // convert x: 2M elements, 8/thread
    int g = bid * 256 + threadIdx.x;
    const float4* p = (const float4*)x;
    float4 f0 = p[g * 2], f1 = p[g * 2 + 1];
    union { unsigned short u[8]; uint4 v; } pk;
    pk.u[0]=f2bf(f0.x); pk.u[1]=f2bf(f0.y); pk.u[2]=f2bf(f0.z); pk.u[3]=f2bf(f0.w);
    pk.u[4]=f2bf(f1.x); pk.u[5]=f2bf(f1.y); pk.u[6]=f2bf(f1.z); pk.u[7]=f2bf(f1.w);
    ((uint4*)x_bf)[g] = pk.v;
  } else if (bid < 1024 + 768) {          // Wqkv [512,1536] -> [1536,512]
    transpose_body(bid - 1024, C3 / 32, Wqkv, wqkv_t, CC, C3);
  } else {                                // Wproj [512,512] -> ^T
    transpose_body(bid - 1792, CC / 32, Wproj, wproj_t, CC, CC);
  }
}

// ---------------------------------------------------------------------------
// Kernel 2: GEMM1 (qkv, bf16 out) blocks [0,768) + topk blocks [768,768+4096)
// ---------------------------------------------------------------------------
__global__ __launch_bounds__(256) void gemm1_topk_kernel(
    const unsigned short* __restrict__ x_bf,
    const unsigned short* __restrict__ wqkv_t,
    const float* __restrict__ bqkv, unsigned short* __restrict__ qkv_bf,
    const float* __restrict__ tau, int* __restrict__ idx_out) {
  if (blockIdx.x < G1_BLOCKS)
    gemm_body<true>(blockIdx.x, G1_NT, x_bf, wqkv_t, bqkv, qkv_bf, C3, CC);
  else
    topk_body(blockIdx.x - G1_BLOCKS, tau, idx_out);
}

// ---------------------------------------------------------------------------
// Kernel 3: sparse attention (round-5 proven): prefetched gathers,
// interleaved shuffle reductions. 512 thr: wave h = head h, lane = d.
// ---------------------------------------------------------------------------
__global__ __launch_bounds__(512) void attn_kernel(
    const unsigned short* __restrict__ qkv, const float* __restrict__ tau,
    const int* __restrict__ idx_in, unsigned short* __restrict__ attn_bf,
    float* __restrict__ sig_out) {
  const int row  = blockIdx.x;          // b*T + t
  const int b    = row >> 11;
  const int tid  = threadIdx.x;
  const int h    = tid >> 6;
  const int lane = tid & 63;

  __shared__ int   idx4[KK];
  __shared__ float tau4[KK];
  __shared__ float ps[HH][KK];
  if (tid < KK) {
    int s = idx_in[row * KK + tid];
    idx4[tid] = s;
    tau4[tid] = tau[(size_t)row * TT + s];
  }
  __syncthreads();

  const float q = bf2f(qkv[(size_t)row * C3 + h * DD + lane]);
  float kv[KK], vv[KK];
#pragma unroll
  for (int j = 0; j < KK; ++j) {
    size_t bs = ((size_t)(b * TT + idx4[j])) * C3 + h * DD + lane;
    kv[j] = bf2f(qkv[bs + CC]);
    vv[j] = bf2f(qkv[bs + 2 * CC]);
  }

  float p[KK];
#pragma unroll
  for (int j = 0; j < KK; ++j) p[j] = q * kv[j];
#pragma unroll
  for (int off = 32; off > 0; off >>= 1)
#pragma unroll
    for (int j = 0; j < KK; ++j) p[j] += __shfl_xor(p[j], off, 64);

  float logit[KK];
#pragma unroll
  for (int j = 0; j < KK; ++j)
    logit[j] = p[j] * 0.125f + 2.5f * logf(tau4[j] + 1e-8f);

  float m = fmaxf(fmaxf(logit[0], logit[1]), fmaxf(logit[2], logit[3]));
  float den = 0.f;
#pragma unroll
  for (int j = 0; j < KK; ++j) { p[j] = expf(logit[j] - m); den += p[j]; }
  float inv = 1.f / den;
#pragma unroll
  for (int j = 0; j < KK; ++j) p[j] *= inv;

  float o = 0.f;
#pragma unroll
  for (int j = 0; j < KK; ++j) o += p[j] * vv[j];
  attn_bf[(size_t)row * CC + h * DD + lane] = f2bf(o);

  if (lane < KK) ps[h][lane] = p[lane];
  __syncthreads();
  if (tid < KK) {
    float s = 0.f;
#pragma unroll
    for (int k = 0; k < HH; ++k) s += ps[k][tid];
    sig_out[row * KK + tid] = s * (1.0f / HH);
  }
}

// ---------------------------------------------------------------------------
// Kernel 4: GEMM2 (out, fp32) blocks [0,256) + tau update blocks [256,256+4096)
// ---------------------------------------------------------------------------
__global__ __launch_bounds__(256) void gemm2_tau_kernel(
    const unsigned short* __restrict__ attn_bf,
    const unsigned short* __restrict__ wproj_t,
    const float* __restrict__ bproj, float* __restrict__ out,
    const float* __restrict__ tau, const int* __restrict__ idx_in,
    const float* __restrict__ sig_in, float* __restrict__ tau_out) {
  if (blockIdx.x < G2_BLOCKS)
    gemm_body<false>(blockIdx.x, G2_NT, attn_bf, wproj_t, bproj, out, CC, CC);
  else
    tau_body(blockIdx.x - G2_BLOCKS, tau, idx_in, sig_in, tau_out);
}

// ---------------------------------------------------------------------------
extern "C" void kernel_launch(void* const* d_in, const int* in_sizes, int n_in,
                              void* d_out, int out_size, void* d_ws, size_t ws_size,
                              hipStream_t stream) {
  const float* x     = (const float*)d_in[0];   // [B,T,C]
  const float* tau   = (const float*)d_in[1];   // [B,T,T]
  const float* Wqkv  = (const float*)d_in[2];   // [C,3C]
  const float* bqkv  = (const float*)d_in[3];   // [3C]
  const float* Wproj = (const float*)d_in[4];   // [C,C]
  const float* bproj = (const float*)d_in[5];   // [C]

  float* out     = (float*)d_out;               // [B,T,C]
  float* tau_new = out + (size_t)MROWS * CC;    // [B,T,T]

  char* w = (char*)d_ws;
  unsigned short* qkv_bf  = (unsigned short*)w; w += (size_t)MROWS * C3 * 2;
  unsigned short* x_bf    = (unsigned short*)w; w += (size_t)MROWS * CC * 2;
  unsigned short* wqkv_t  = (unsigned short*)w; w += (size_t)C3 * CC * 2;
  unsigned short* wproj_t = (unsigned short*)w; w += (size_t)CC * CC * 2;
  unsigned short* attn_bf = (unsigned short*)w; w += (size_t)MROWS * CC * 2;
  int*   idx = (int*)w;                  w += (size_t)MROWS * KK * 4;
  float* sig = (float*)w;

  // 1) converts: x->bf16, Wqkv^T, Wproj^T
  prep_kernel<<<2048, 256, 0, stream>>>(x, x_bf, Wqkv, wqkv_t, Wproj, wproj_t);

  // 2) qkv GEMM (bf16 out) + fast top-4 of tau rows, co-scheduled
  gemm1_topk_kernel<<<G1_BLOCKS + MROWS, 256, 0, stream>>>(
      x_bf, wqkv_t, bqkv, qkv_bf, tau, idx);

  // 3) sparse attention + signal
  attn_kernel<<<MROWS, 512, 0, stream>>>(qkv_bf, tau, idx, attn_bf, sig);

  // 4) out GEMM (fp32) + tau update, co-scheduled
  gemm2_tau_kernel<<<G2_BLOCKS + MROWS, 256, 0, stream>>>(
      attn_bf, wproj_t, bproj, out, tau, idx, sig, tau_new);
}